// Round 16
// baseline (79.835 us; speedup 1.0000x reference)
//
#include <hip/hip_runtime.h>
#include <hip/hip_bf16.h>

// CantorMultiheadFusion: x -> QKV proj -> sliding-window(K=64, clipped) MHA -> out proj (+bias)
// B=2 S=2048 DIM=1024 H=16 D=64 K=64
//
// Pipeline (4 launches):
//  1) cvt_w: f32->bf16 for [Wq;Wk;Wv], Wo (weights only)
//  2) gemm256: qkv bf16 = cvt(x) @ Wqkv^T (256x192, 8 waves, BK=64, counted-vmcnt 2-phase;
//     A loaded f32 -> in-reg RNE cvt -> ds_write into swizzled LDS, SINGLE reg set,
//     A-loads issued BEFORE stageB so VMCNT3 retires them without draining B;
//     B via global_load_lds). V-range columns -> transposed store into Vt.
//  3) attn_fused: 4 waves x 32 q-rows, block-shared K/V LDS staging (R11/R13 proven)
//  4) gemm_out: out f32 = attn @ Wo^T + bo (64x128 tile, vmcnt(3), grid 512 = 2/CU)

typedef __attribute__((ext_vector_type(8))) short bf16x8;
typedef __attribute__((ext_vector_type(4))) float f32x4;

__device__ __forceinline__ unsigned short f32_to_bf16_rne(float f) {
    unsigned u = __float_as_uint(f);
    u += 0x7FFFu + ((u >> 16) & 1u);
    return (unsigned short)(u >> 16);
}
__device__ __forceinline__ float bf16_to_f32(unsigned short s) {
    return __uint_as_float(((unsigned)s) << 16);
}

#define VMCNT3 asm volatile("s_waitcnt vmcnt(3)" ::: "memory")
#define VMCNT0 asm volatile("s_waitcnt vmcnt(0)" ::: "memory")
#define LGKM0  asm volatile("s_waitcnt lgkmcnt(0)" ::: "memory")
#define MEMFENCE asm volatile("" ::: "memory")
#define BAR __builtin_amdgcn_s_barrier()

// ---------------- weight conversion kernel ----------------
__global__ __launch_bounds__(256) void cvt_w(
    const float4* __restrict__ Wq, const float4* __restrict__ Wk,
    const float4* __restrict__ Wv, const float4* __restrict__ Wo,
    ushort4* __restrict__ wqkv, ushort4* __restrict__ wob) {
    const int WN = (1024 * 1024) / 4;
    int i = blockIdx.x * 256 + threadIdx.x;
    int w = i >> 18;
    int k = i & (WN - 1);
    const float4* s = (w == 0) ? Wq : (w == 1) ? Wk : (w == 2) ? Wv : Wo;
    float4 v = s[k];
    ushort4 o;
    o.x = f32_to_bf16_rne(v.x);
    o.y = f32_to_bf16_rne(v.y);
    o.z = f32_to_bf16_rne(v.z);
    o.w = f32_to_bf16_rne(v.w);
    ushort4* dst = (w < 3) ? (wqkv + (size_t)w * WN + k) : (wob + k);
    *dst = o;
}

// ---------------- 256x192 8-wave counted-vmcnt NT GEMM, A from f32 ----------------
// C = cvt(X[M][K]) * B[N][K]^T. Per tile t (2 phases):
//  ph0: VMCNT0 (retires B(t), only thing outstanding) + BAR; ALOAD A(t+1) f32 (8 loads);
//       LDS-read cur ks0; stageB(t+1) (3 gload_lds); 24 MFMA.
//  ph1: VMCNT3 (retires the 8 older A-loads; B(t+1) flies) + BAR; AWRITE A(t+1) -> nxt
//       (cvt + ds_write, swizzled); LDS-read cur ks1; 24 MFMA; LGKM0 + BAR.
__global__ __launch_bounds__(512, 2) void gemm256(
    const float* __restrict__ X, const ushort* __restrict__ B,
    ushort* __restrict__ C, ushort* __restrict__ Vt, int M, int N, int K) {
    __shared__ ushort smem[57344];   // 112 KB

    const int t = threadIdx.x;
    const int l = t & 63, w = t >> 6;
    const int wm = w >> 2, wn = w & 3;     // 2 x 4 waves -> wave tile 128 x 48
    const int c15 = l & 15, g = l >> 4;
    const int bid = blockIdx.x;
    const int swz = (bid & 7) * 32 + (bid >> 3);
    const int mBase = (swz >> 4) * 256, nBase = (swz & 15) * 192;
    const int NT = K >> 6;

    // A staging geometry (2 chunks/thread per k-half; [256 rows][32 k], row-pair swizzle)
    int rrA[2], k8A[2];
#pragma unroll
    for (int j = 0; j < 2; ++j) {
        const int L = (w * 2 + j) * 1024 + l * 16;
        const int rp = L >> 7;
        const int gl = ((L >> 4) & 7) ^ (rp & 7);
        rrA[j] = rp * 2 + (gl >> 2);
        k8A[j] = (gl & 3) * 8;
    }
    // B staging geometry (3 chunks, [192 rows][64 k], row swizzle)
    int rrB[3], k8B[3];
#pragma unroll
    for (int c = 0; c < 3; ++c) {
        const int G = c * 512 + w * 64 + l;
        const int row = G >> 3;
        rrB[c] = row;
        k8B[c] = ((G & 7) ^ (row & 7)) * 8;
    }

    int aOff[8], bOff0[3], bOff1[3];
#pragma unroll
    for (int m8 = 0; m8 < 8; ++m8) {
        const int R = wm * 128 + m8 * 16 + c15;
        const int rp = R >> 1;
        aOff[m8] = rp * 64 + ((((R & 1) << 2) | g) ^ (rp & 7)) * 8;
    }
#pragma unroll
    for (int n3 = 0; n3 < 3; ++n3) {
        const int R = wn * 48 + n3 * 16 + c15;
        bOff0[n3] = R * 64 + ((g) ^ (R & 7)) * 8;
        bOff1[n3] = R * 64 + ((4 | g) ^ (R & 7)) * 8;
    }

    f32x4 acc[8][3] = {};
    bf16x8 aF[8], bF[3];
    float4 ar[8];   // single A reg set: [kh*4 + j*2 + half]

    auto stageB = [&](int dbuf, int kt) {
#pragma unroll
        for (int c = 0; c < 3; ++c) {
            const ushort* src = B + (size_t)(nBase + rrB[c]) * K + kt * 64 + k8B[c];
            __builtin_amdgcn_global_load_lds(
                (const __attribute__((address_space(1))) void*)src,
                (__attribute__((address_space(3))) void*)
                    &smem[dbuf * 28672 + 16384 + c * 4096 + w * 512 + l * 8],
                16, 0, 0);
        }
    };

#define ALOAD(KT)                                                               \
    {                                                                           \
        _Pragma("unroll") for (int kh = 0; kh < 2; ++kh)                        \
            _Pragma("unroll") for (int j = 0; j < 2; ++j) {                     \
                const float* sa = X + (size_t)(mBase + rrA[j]) * K +            \
                                  (KT) * 64 + kh * 32 + k8A[j];                 \
                ar[kh * 4 + j * 2 + 0] = *reinterpret_cast<const float4*>(sa);  \
                ar[kh * 4 + j * 2 + 1] = *reinterpret_cast<const float4*>(sa + 4); \
            }                                                                   \
    }
#define AWRITE(DBUF, KH)                                                        \
    {                                                                           \
        _Pragma("unroll") for (int j = 0; j < 2; ++j) {                         \
            bf16x8 o;                                                           \
            const float4 a0 = ar[(KH) * 4 + j * 2 + 0];                         \
            const float4 a1 = ar[(KH) * 4 + j * 2 + 1];                         \
            o[0] = (short)f32_to_bf16_rne(a0.x); o[1] = (short)f32_to_bf16_rne(a0.y); \
            o[2] = (short)f32_to_bf16_rne(a0.z); o[3] = (short)f32_to_bf16_rne(a0.w); \
            o[4] = (short)f32_to_bf16_rne(a1.x); o[5] = (short)f32_to_bf16_rne(a1.y); \
            o[6] = (short)f32_to_bf16_rne(a1.z); o[7] = (short)f32_to_bf16_rne(a1.w); \
            *reinterpret_cast<bf16x8*>(                                         \
                &smem[(DBUF) * 28672 + (KH) * 8192 + (w * 2 + j) * 512 + l * 8]) = o; \
        }                                                                       \
    }
#define LOAD_AF(CUR, KH)                                                        \
    {                                                                           \
        const int ab = (CUR) * 28672 + (KH) * 8192;                             \
        _Pragma("unroll") for (int m8 = 0; m8 < 8; ++m8)                        \
            aF[m8] = *reinterpret_cast<const bf16x8*>(&smem[ab + aOff[m8]]);    \
    }
#define LOAD_BF(CUR, KH)                                                        \
    {                                                                           \
        const int bb = (CUR) * 28672 + 16384;                                   \
        _Pragma("unroll") for (int n = 0; n < 3; ++n)                           \
            bF[n] = *reinterpret_cast<const bf16x8*>(                           \
                &smem[bb + ((KH) ? bOff1[n] : bOff0[n])]);                      \
    }
#define DO_MFMA()                                                               \
    __builtin_amdgcn_s_setprio(1);                                              \
    _Pragma("unroll") for (int m8 = 0; m8 < 8; ++m8) {                          \
        _Pragma("unroll") for (int n = 0; n < 3; ++n)                           \
            acc[m8][n] = __builtin_amdgcn_mfma_f32_16x16x32_bf16(               \
                aF[m8], bF[n], acc[m8][n], 0, 0, 0);                            \
    }                                                                           \
    __builtin_amdgcn_s_setprio(0);

    // prologue: A(0) -> regs -> LDS buf0 (compiler waits the f32 loads); B(0) staged.
    ALOAD(0);
    AWRITE(0, 0);
    AWRITE(0, 1);
    stageB(0, 0);
    LGKM0;   // A(0) ds_writes complete (barrier at tile-0 entry publishes them)

    for (int kt = 0; kt < NT - 1; ++kt) {
        const int cur = kt & 1, nxt = cur ^ 1;
        // ph0: B(t) is the only outstanding vmem -> drain it; publish A writes.
        VMCNT0;
        BAR; MEMFENCE;
        ALOAD(kt + 1);                 // 8 f32 loads, oldest in queue
        LOAD_AF(cur, 0);
        LOAD_BF(cur, 0);
        stageB(nxt, kt + 1);           // +3 gload_lds (newer than A loads)
        DO_MFMA();
        // ph1: retire the 8 A-loads (older); leave B(t+1) x3 in flight.
        VMCNT3;
        BAR; MEMFENCE;
        AWRITE(nxt, 0);
        AWRITE(nxt, 1);
        LOAD_AF(cur, 1);
        LOAD_BF(cur, 1);
        DO_MFMA();
        LGKM0;                         // A ds_writes + LDS reads drained
        BAR; MEMFENCE;
    }

    // tail tile NT-1 (A already in LDS; only B(NT-1) outstanding)
    {
        const int cur = (NT - 1) & 1;
        VMCNT0;
        BAR; MEMFENCE;
        LOAD_AF(cur, 0);
        LOAD_BF(cur, 0);
        DO_MFMA();
        LOAD_AF(cur, 1);
        LOAD_BF(cur, 1);
        DO_MFMA();
    }

    const int bb_ = mBase >> 11;
#pragma unroll
    for (int m8 = 0; m8 < 8; ++m8) {
        const int row = mBase + wm * 128 + m8 * 16 + g * 4;
        const int s0 = (mBase & 2047) + wm * 128 + m8 * 16 + g * 4;
#pragma unroll
        for (int n3 = 0; n3 < 3; ++n3) {
            const int col = nBase + wn * 48 + n3 * 16 + c15;
            if (col < 2048) {
#pragma unroll
                for (int r = 0; r < 4; ++r)
                    C[(size_t)(row + r) * N + col] = f32_to_bf16_rne(acc[m8][n3][r]);
            } else {
                const int vcol = col - 2048;
                const int hh = vcol >> 6, dd = vcol & 63;
                ushort4 vv;
                vv.x = f32_to_bf16_rne(acc[m8][n3][0]);
                vv.y = f32_to_bf16_rne(acc[m8][n3][1]);
                vv.z = f32_to_bf16_rne(acc[m8][n3][2]);
                vv.w = f32_to_bf16_rne(acc[m8][n3][3]);
                *reinterpret_cast<ushort4*>(
                    &Vt[(((size_t)(bb_ * 16 + hh) * 64 + dd) << 11) + s0]) = vv;
            }
        }
    }
#undef ALOAD
#undef AWRITE
#undef LOAD_AF
#undef LOAD_BF
#undef DO_MFMA
}

// ---------------- 64x128 4-wave counted-vmcnt NT GEMM (f32 + bias out) ----------------
__global__ __launch_bounds__(256, 3) void gemm_out(
    const ushort* __restrict__ A, const ushort* __restrict__ B,
    float* __restrict__ C, const float* __restrict__ bias, int M, int N, int K) {
    __shared__ ushort smem[24576];   // 48 KB

    const int t = threadIdx.x;
    const int l = t & 63, w = t >> 6;      // 4 waves
    const int wm = w >> 1, wn = w & 1;     // 2 x 2
    const int c15 = l & 15, g = l >> 4;
    const int bid = blockIdx.x;            // 512 blocks
    const int swz = (bid & 7) * 64 + (bid >> 3);
    const int mBase = (swz >> 3) * 64, nBase = (swz & 7) * 128;
    const int NT = K >> 6;

    int rA_, k8A_;
    {
        const int L = w * 1024 + l * 16;
        const int rp = L >> 7;
        const int gl = ((L >> 4) & 7) ^ (rp & 7);
        rA_ = rp * 2 + (gl >> 2);
        k8A_ = (gl & 3) * 8;
    }
    int rB_[2], k8B_[2];
#pragma unroll
    for (int j = 0; j < 2; ++j) {
        const int L = (w * 2 + j) * 1024 + l * 16;
        const int rp = L >> 7;
        const int gl = ((L >> 4) & 7) ^ (rp & 7);
        rB_[j] = rp * 2 + (gl >> 2);
        k8B_[j] = (gl & 3) * 8;
    }

    int aOff[2], bOff[4];
#pragma unroll
    for (int m2 = 0; m2 < 2; ++m2) {
        const int R = wm * 32 + m2 * 16 + c15;
        const int rp = R >> 1;
        aOff[m2] = rp * 64 + ((((R & 1) << 2) | g) ^ (rp & 7)) * 8;
    }
#pragma unroll
    for (int n4 = 0; n4 < 4; ++n4) {
        const int R = wn * 64 + n4 * 16 + c15;
        const int rp = R >> 1;
        bOff[n4] = rp * 64 + ((((R & 1) << 2) | g) ^ (rp & 7)) * 8;
    }

    f32x4 acc[2][4] = {};
    bf16x8 aF[2], bF0[2], bF1[2];

    auto stage = [&](int dbuf, int kh, int kt) {
        const ushort* sa = A + (size_t)(mBase + rA_) * K + kt * 64 + kh * 32 + k8A_;
        __builtin_amdgcn_global_load_lds(
            (const __attribute__((address_space(1))) void*)sa,
            (__attribute__((address_space(3))) void*)
                &smem[dbuf * 12288 + kh * 2048 + w * 512 + l * 8],
            16, 0, 0);
#pragma unroll
        for (int j = 0; j < 2; ++j) {
            const ushort* sb = B + (size_t)(nBase + rB_[j]) * K + kt * 64 + kh * 32 + k8B_[j];
            __builtin_amdgcn_global_load_lds(
                (const __attribute__((address_space(1))) void*)sb,
                (__attribute__((address_space(3))) void*)
                    &smem[dbuf * 12288 + 4096 + kh * 4096 + (w * 2 + j) * 512 + l * 8],
                16, 0, 0);
        }
    };

#define LOAD_AF2(CUR, KS)                                                       \
    {                                                                           \
        const int ab = (CUR) * 12288 + (KS) * 2048;                             \
        _Pragma("unroll") for (int m2 = 0; m2 < 2; ++m2)                        \
            aF[m2] = *reinterpret_cast<const bf16x8*>(&smem[ab + aOff[m2]]);    \
    }
#define LOAD_BF2(DST, CUR, KS, NH)                                              \
    {                                                                           \
        const int bb = (CUR) * 12288 + 4096 + (KS) * 4096;                      \
        _Pragma("unroll") for (int n = 0; n < 2; ++n)                           \
            DST[n] = *reinterpret_cast<const bf16x8*>(&smem[bb + bOff[(NH) * 2 + n]]); \
    }
#define DO_MFMA2(NH, BF)                                                        \
    __builtin_amdgcn_s_setprio(1);                                              \
    _Pragma("unroll") for (int m2 = 0; m2 < 2; ++m2) {                          \
        _Pragma("unroll") for (int n = 0; n < 2; ++n)                           \
            acc[m2][(NH) * 2 + n] = __builtin_amdgcn_mfma_f32_16x16x32_bf16(    \
                aF[m2], BF[n], acc[m2][(NH) * 2 + n], 0, 0, 0);                 \
    }                                                                           \
    __builtin_amdgcn_s_setprio(0);

    stage(0, 0, 0);
    stage(0, 1, 0);

    for (int kt = 0; kt < NT - 1; ++kt) {
        const int cur = kt & 1, nxt = cur ^ 1;
        VMCNT3;
        BAR; MEMFENCE;
        LOAD_AF2(cur, 0);
        LOAD_BF2(bF0, cur, 0, 0);
        stage(nxt, 0, kt + 1);
        DO_MFMA2(0, bF0);
        LOAD_BF2(bF1, cur, 0, 1);
        DO_MFMA2(1, bF1);
        VMCNT3;
        BAR; MEMFENCE;
        LOAD_AF2(cur, 1);
        LOAD_BF2(bF0, cur, 1, 0);
        stage(nxt, 1, kt + 1);
        DO_MFMA2(0, bF0);
        LOAD_BF2(bF1, cur, 1, 1);
        DO_MFMA2(1, bF1);
    }

    {
        const int cur = (NT - 1) & 1;
        VMCNT3;
        BAR; MEMFENCE;
        LOAD_AF2(cur, 0);
        LOAD_BF2(bF0, cur, 0, 0);
        DO_MFMA2(0, bF0);
        LOAD_BF2(bF1, cur, 0, 1);
        DO_MFMA2(1, bF1);
        VMCNT0;
        BAR; MEMFENCE;
        LOAD_AF2(cur, 1);
        LOAD_BF2(bF0, cur, 1, 0);
        DO_MFMA2(0, bF0);
        LOAD_BF2(bF1, cur, 1, 1);
        DO_MFMA2(1, bF1);
    }

#pragma unroll
    for (int m2 = 0; m2 < 2; ++m2) {
#pragma unroll
        for (int n4 = 0; n4 < 4; ++n4) {
            const int col = nBase + wn * 64 + n4 * 16 + c15;
#pragma unroll
            for (int r = 0; r < 4; ++r) {
                const int row = mBase + wm * 32 + m2 * 16 + g * 4 + r;
                C[(size_t)row * N + col] = acc[m2][n4][r] + bias[col];
            }
        }
    }
#undef LOAD_AF2
#undef LOAD_BF2
#undef DO_MFMA2
}

// ---------------- banded MFMA attention, block-shared K/V LDS staging ----------------
#define PADW 104
__global__ __launch_bounds__(256, 2) void attn_fused(
    const ushort* __restrict__ qkv, const ushort* __restrict__ Vt,
    ushort* __restrict__ attn_out) {
    __shared__ ushort K_lds[192 * 64];        // 24 KB
    __shared__ ushort V_lds[64 * 192];        // 24 KB
    __shared__ ushort P_lds[4][32 * PADW];    // 26.6 KB

    const int t = threadIdx.x;
    const int lane = t & 63;
    const int wib  = t >> 6;
    const int bid = blockIdx.x;               // 512 blocks, %8==0 -> bijective
    const int swz = (bid & 7) * 64 + (bid >> 3);
    const int qc = swz & 15;
    const int h  = (swz >> 4) & 15;
    const int b  = swz >> 8;
    const int Qs = qc * 128;
    const int qs = Qs + wib * 32;
    const int kstart = qs - 32;
    const int c15 = lane & 15, g = lane >> 4;
    const int qb = qs >> 5;
    const bool edge = (qb == 0) || (qb == 63);

    const ushort* Qbase = qkv + (size_t)(b * 2048 + qs) * 3072 + h * 64;
    bf16x8 qf[2][2];
#pragma unroll
    for (int qt = 0; qt < 2; ++qt)
#pragma unroll
        for (int dc = 0; dc < 2; ++dc)
            qf[qt][dc] = *reinterpret_cast<const bf16x8*>(
                Qbase + (size_t)(qt * 16 + c15) * 3072 + dc * 32 + g * 8);

    const ushort* Kglob = qkv + (size_t)b * 2048 * 3072 + 1024 + h * 64;
#pragma unroll
    for (int c = 0; c < 6; ++c) {
        const int G = c * 256 + t;
        const int row = G >> 3, gp = G & 7;
        const int col16 = gp ^ (row & 7);
        int s = Qs - 32 + row;
        s = min(max(s, 0), 2047);
        __builtin_amdgcn_global_load_lds(
            (const __attribute__((address_space(1))) void*)(Kglob + (size_t)s * 3072 + col16 * 8),
            (__attribute__((address_space(3))) void*)&K_lds[G * 8], 16, 0, 0);
    }
    const ushort* Vglob = Vt + ((size_t)(b * 16 + h) * 64) * 2048;
#pragma unroll
    for (int c = 0; c < 6; ++c) {
        const int L = c * 256 + t;
        const int row = L / 24, gp = L % 24;
        const int lg = gp ^ (row & 7);
        int s = Qs - 32 + lg * 8;
        s = min(max(s, 0), 2040);
        __builtin_amdgcn_global_load_lds(
            (const __attribute__((address_space(1))) void*)(Vglob + (size_t)row * 2048 + s),
            (__attribute__((address_space(3))) void*)&V_lds[L * 8], 16, 0, 0);
    }
    __syncthreads();

    f32x4 accS[6][2] = {};
#pragma unroll
    for (int kt = 0; kt < 6; ++kt) {
        const int krl = wib * 32 + kt * 16 + c15;
#pragma unroll
        for (int dc = 0; dc < 2; ++dc) {
            bf16x8 kf = *reinterpret_cast<const bf16x8*>(
                &K_lds[krl * 64 + ((((dc << 2) | g)) ^ (krl & 7)) * 8]);
#pragma unroll
            for (int qt = 0; qt < 2; ++qt)
                accS[kt][qt] = __builtin_amdgcn_mfma_f32_16x16x32_bf16(
                    kf, qf[qt][dc], accS[kt][qt], 0, 0, 0);
        }
    }

    float mx[2] = {-1e30f, -1e30f};
    if (edge) {
#pragma unroll
        for (int kt = 0; kt < 6; ++kt)
#pragma unroll
            for (int qt = 0; qt < 2; ++qt)
#pragma unroll
                for (int r = 0; r < 4; ++r) {
                    const int vk = kt * 16 + g * 4 + r;
                    const int qi = qt * 16 + c15;
                    const int ki = kstart + vk;
                    const int s_row = qs + qi;
                    float val = -1e30f;
                    if (vk >= qi && vk <= qi + 63 && ki >= 0 && ki <= 2047) {
                        float bias = 0.f;
                        if (ki == 0 && s_row <= 32)
                            bias = __logf((float)(33 - s_row));
                        if (ki == 2047 && s_row >= 2016)
                            bias = __logf((float)(s_row - 2015));
                        val = accS[kt][qt][r] * 0.125f + bias;
                    }
                    accS[kt][qt][r] = val;
                    mx[qt] = fmaxf(mx[qt], val);
                }
    } else {
#pragma unroll
        for (int kt = 0; kt < 6; ++kt)
#pragma unroll
            for (int qt = 0; qt < 2; ++qt)
#pragma unroll
                for (int r = 0; r < 4; ++r) {
                    const int vk = kt * 16 + g * 4 + r;
                    const int qi = qt * 16 + c15;
                    float val = -1e30f;
                    if (vk >= qi && vk <= qi + 63)
                        val = accS[kt][qt][r] * 0.125f;
                    accS[kt][qt][r] = val;
                    mx[qt] = fmaxf(mx[qt], val);
                }
    }
#pragma unroll
    for (int qt = 0; qt < 2; ++qt) {
        mx[qt] = fmaxf(mx[qt], __shfl_xor(mx[qt], 16));
        mx[qt] = fmaxf(mx[qt], __shfl_xor(mx[qt], 32));
    }

    float sum[2] = {0.f, 0.f};
#pragma unroll
    for (int kt = 0; kt < 6; ++kt)
#pragma unroll
        for (int qt = 0; qt < 2; ++qt)
#pragma unroll
            for (int r = 0; r < 4; ++r) {
                float p = __expf(accS[kt][qt][r] - mx[qt]);
                accS[kt][qt][r] = p;
                sum[qt] += p;
            }
#pragma unroll
    for (int qt = 0; qt < 2; ++qt) {
        sum[qt] += __shfl_xor(sum[qt], 16);
        sum[qt] += __shfl_xor(sum[qt], 32);
        sum[qt] = 1.f / sum[qt];
    }

#pragma unroll
    for (int kt = 0; kt < 6; ++kt)
#pragma unroll
        for (int qt = 0; qt < 2; ++qt)
#pragma unroll
            for (int r = 0; r < 4; ++r) {
                const int vk = kt * 16 + g * 4 + r;
                const int qi = qt * 16 + c15;
                P_lds[wib][qi * PADW + vk] = f32_to_bf16_rne(accS[kt][qt][r] * sum[qt]);
            }

    f32x4 accO[2][4] = {};
#pragma unroll
    for (int u = 0; u < 3; ++u) {
        bf16x8 pf[2];
#pragma unroll
        for (int qt = 0; qt < 2; ++qt)
            pf[qt] = *reinterpret_cast<const bf16x8*>(
                &P_lds[wib][(qt * 16 + c15) * PADW + u * 32 + g * 8]);
        const int j = 4 * (wib + u) + g;
#pragma unroll
        for (int dt = 0; dt < 4; ++dt) {
            const int vrow = dt * 16 + c15;
            bf16x8 vf = *reinterpret_cast<const bf16x8*>(
                &V_lds[vrow * 192 + ((j ^ (vrow & 7)) * 8)]);
#pragma unroll
            for (int qt = 0; qt < 2; ++qt)
                accO[qt][dt] = __builtin_amdgcn_mfma_f32_16x16x32_bf16(
                    pf[qt], vf, accO[qt][dt], 0, 0, 0);
        }
    }

#pragma unroll
    for (int qt = 0; qt < 2; ++qt)
#pragma unroll
        for (int dt = 0; dt < 4; ++dt)
#pragma unroll
            for (int r = 0; r < 4; ++r) {
                const int row = b * 2048 + qs + qt * 16 + g * 4 + r;
                const int col = h * 64 + dt * 16 + c15;
                attn_out[(size_t)row * 1024 + col] = f32_to_bf16_rne(accO[qt][dt][r]);
            }
}

// ---------------- launch ----------------
extern "C" void kernel_launch(void* const* d_in, const int* in_sizes, int n_in,
                              void* d_out, int out_size, void* d_ws, size_t ws_size,
                              hipStream_t stream) {
    const float* x  = (const float*)d_in[0];
    const float* Wq = (const float*)d_in[2];
    const float* Wk = (const float*)d_in[3];
    const float* Wv = (const float*)d_in[4];
    const float* Wo = (const float*)d_in[5];
    const float* bo = (const float*)d_in[6];

    const int M = 4096;
    const int DIM = 1024;

    ushort* Wqkv = (ushort*)d_ws;                 // 3072*1024
    ushort* Wob  = Wqkv + (size_t)3072 * 1024;    // 1024*1024
    ushort* qkv  = Wob + (size_t)1024 * 1024;     // 4096*3072 (V-range unused)
    ushort* attn = qkv + (size_t)M * 3072;        // 4096*1024
    ushort* Vt   = attn + (size_t)M * DIM;        // 2*16*64*2048

    cvt_w<<<4096, 256, 0, stream>>>(
        (const float4*)Wq, (const float4*)Wk, (const float4*)Wv, (const float4*)Wo,
        (ushort4*)Wqkv, (ushort4*)Wob);

    gemm256<<<256, 512, 0, stream>>>(x, Wqkv, qkv, Vt, M, 3072, DIM);

    attn_fused<<<512, 256, 0, stream>>>(qkv, Vt, attn);

    gemm_out<<<512, 256, 0, stream>>>(attn, Wob, (float*)d_out, bo, M, DIM, DIM);
}

// Round 17
// 68.218 us; speedup vs baseline: 1.1703x; 1.1703x over previous
//
#include <hip/hip_runtime.h>
#include <hip/hip_bf16.h>

// CantorMultiheadFusion: x -> QKV proj -> sliding-window(K=64, clipped) MHA -> out proj (+bias)
// B=2 S=2048 DIM=1024 H=16 D=64 K=64
//
// Pipeline (4 launches)  [R13 configuration — best verified: 68.2/68.35/68.33 us]:
//  1) cvt_all: f32->bf16 for x, [Wq;Wk;Wv], Wo
//  2) gemm256: qkv bf16 = x @ Wqkv^T (256x192 tile, grid 256 = 1/CU, BK=64, 8 waves,
//     counted-vmcnt 2-phase, granule-XOR swizzle, XCD-swizzled).
//     V-range columns -> transposed store into Vt.
//  3) attn_fused: 4 waves x 32 q-rows, block-shared K/V LDS staging, Q-hoist
//  4) gemm_out: out f32 = attn @ Wo^T + bo (64x128 tile, vmcnt(3), grid 512 = 2/CU)

typedef __attribute__((ext_vector_type(8))) short bf16x8;
typedef __attribute__((ext_vector_type(4))) float f32x4;

__device__ __forceinline__ unsigned short f32_to_bf16_rne(float f) {
    unsigned u = __float_as_uint(f);
    u += 0x7FFFu + ((u >> 16) & 1u);
    return (unsigned short)(u >> 16);
}
__device__ __forceinline__ float bf16_to_f32(unsigned short s) {
    return __uint_as_float(((unsigned)s) << 16);
}

#define VMCNT3 asm volatile("s_waitcnt vmcnt(3)" ::: "memory")
#define VMCNT2 asm volatile("s_waitcnt vmcnt(2)" ::: "memory")
#define VMCNT0 asm volatile("s_waitcnt vmcnt(0)" ::: "memory")
#define MEMFENCE asm volatile("" ::: "memory")
#define BAR __builtin_amdgcn_s_barrier()

// ---------------- merged conversion kernel ----------------
__global__ __launch_bounds__(256) void cvt_all(
    const float4* __restrict__ x,
    const float4* __restrict__ Wq, const float4* __restrict__ Wk,
    const float4* __restrict__ Wv, const float4* __restrict__ Wo,
    ushort4* __restrict__ xb, ushort4* __restrict__ wqkv,
    ushort4* __restrict__ wob) {
    const int XN = (4096 * 1024) / 4;
    const int WN = (1024 * 1024) / 4;
    int i = blockIdx.x * 256 + threadIdx.x;
    float4 v;
    ushort4* dst;
    if (i < XN) {
        v = x[i];
        dst = xb + i;
    } else {
        int j = i - XN;
        int w = j >> 18;
        int k = j & (WN - 1);
        const float4* s = (w == 0) ? Wq : (w == 1) ? Wk : (w == 2) ? Wv : Wo;
        v = s[k];
        dst = (w < 3) ? (wqkv + (size_t)w * WN + k) : (wob + k);
    }
    ushort4 o;
    o.x = f32_to_bf16_rne(v.x);
    o.y = f32_to_bf16_rne(v.y);
    o.z = f32_to_bf16_rne(v.z);
    o.w = f32_to_bf16_rne(v.w);
    *dst = o;
}

// ---------------- 256x192 8-wave counted-vmcnt NT GEMM (R8/R11 2-phase) ----------------
__global__ __launch_bounds__(512, 2) void gemm256(
    const ushort* __restrict__ A, const ushort* __restrict__ B,
    ushort* __restrict__ C, ushort* __restrict__ Vt, int M, int N, int K) {
    __shared__ ushort smem[57344];   // 112 KB

    const int t = threadIdx.x;
    const int l = t & 63, w = t >> 6;
    const int wm = w >> 2, wn = w & 3;     // 2 x 4 waves -> wave tile 128 x 48
    const int c15 = l & 15, g = l >> 4;
    const int bid = blockIdx.x;
    const int swz = (bid & 7) * 32 + (bid >> 3);
    const int mBase = (swz >> 4) * 256, nBase = (swz & 15) * 192;
    const int NT = K >> 6;

    int rrA[2], k8A[2];
#pragma unroll
    for (int j = 0; j < 2; ++j) {
        const int L = (w * 2 + j) * 1024 + l * 16;
        const int rp = L >> 7;
        const int gl = ((L >> 4) & 7) ^ (rp & 7);
        rrA[j] = rp * 2 + (gl >> 2);
        k8A[j] = (gl & 3) * 8;
    }
    int rrB[3], k8B[3];
#pragma unroll
    for (int c = 0; c < 3; ++c) {
        const int G = c * 512 + w * 64 + l;
        const int row = G >> 3;
        rrB[c] = row;
        k8B[c] = ((G & 7) ^ (row & 7)) * 8;
    }

    int aOff[8], bOff0[3], bOff1[3];
#pragma unroll
    for (int m8 = 0; m8 < 8; ++m8) {
        const int R = wm * 128 + m8 * 16 + c15;
        const int rp = R >> 1;
        aOff[m8] = rp * 64 + ((((R & 1) << 2) | g) ^ (rp & 7)) * 8;
    }
#pragma unroll
    for (int n3 = 0; n3 < 3; ++n3) {
        const int R = wn * 48 + n3 * 16 + c15;
        bOff0[n3] = R * 64 + ((g) ^ (R & 7)) * 8;
        bOff1[n3] = R * 64 + ((4 | g) ^ (R & 7)) * 8;
    }

    f32x4 acc[8][3] = {};
    bf16x8 aF[8], bF[3];

    auto stageA = [&](int dbuf, int kh, int kt) {
#pragma unroll
        for (int j = 0; j < 2; ++j) {
            const ushort* src = A + (size_t)(mBase + rrA[j]) * K + kt * 64 + kh * 32 + k8A[j];
            __builtin_amdgcn_global_load_lds(
                (const __attribute__((address_space(1))) void*)src,
                (__attribute__((address_space(3))) void*)
                    &smem[dbuf * 28672 + kh * 8192 + (w * 2 + j) * 512 + l * 8],
                16, 0, 0);
        }
    };
    auto stageB = [&](int dbuf, int kt) {
#pragma unroll
        for (int c = 0; c < 3; ++c) {
            const ushort* src = B + (size_t)(nBase + rrB[c]) * K + kt * 64 + k8B[c];
            __builtin_amdgcn_global_load_lds(
                (const __attribute__((address_space(1))) void*)src,
                (__attribute__((address_space(3))) void*)
                    &smem[dbuf * 28672 + 16384 + c * 4096 + w * 512 + l * 8],
                16, 0, 0);
        }
    };

#define LOAD_AF(CUR, KH)                                                        \
    {                                                                           \
        const int ab = (CUR) * 28672 + (KH) * 8192;                             \
        _Pragma("unroll") for (int m8 = 0; m8 < 8; ++m8)                        \
            aF[m8] = *reinterpret_cast<const bf16x8*>(&smem[ab + aOff[m8]]);    \
    }
#define LOAD_BF(CUR, KH)                                                        \
    {                                                                           \
        const int bb = (CUR) * 28672 + 16384;                                   \
        _Pragma("unroll") for (int n = 0; n < 3; ++n)                           \
            bF[n] = *reinterpret_cast<const bf16x8*>(                           \
                &smem[bb + ((KH) ? bOff1[n] : bOff0[n])]);                      \
    }
#define DO_MFMA()                                                               \
    __builtin_amdgcn_s_setprio(1);                                              \
    _Pragma("unroll") for (int m8 = 0; m8 < 8; ++m8) {                          \
        _Pragma("unroll") for (int n = 0; n < 3; ++n)                           \
            acc[m8][n] = __builtin_amdgcn_mfma_f32_16x16x32_bf16(               \
                aF[m8], bF[n], acc[m8][n], 0, 0, 0);                            \
    }                                                                           \
    __builtin_amdgcn_s_setprio(0);

    stageB(0, 0);
    stageA(0, 0, 0);
    stageA(0, 1, 0);

    for (int kt = 0; kt < NT - 1; ++kt) {
        const int cur = kt & 1, nxt = cur ^ 1;
        VMCNT2;
        BAR; MEMFENCE;
        LOAD_AF(cur, 0);
        LOAD_BF(cur, 0);
        stageB(nxt, kt + 1);
        DO_MFMA();
        VMCNT3;
        BAR; MEMFENCE;
        LOAD_AF(cur, 1);
        LOAD_BF(cur, 1);
        stageA(nxt, 0, kt + 1);
        stageA(nxt, 1, kt + 1);
        DO_MFMA();
    }

    {
        const int cur = (NT - 1) & 1;
        VMCNT2;
        BAR; MEMFENCE;
        LOAD_AF(cur, 0);
        LOAD_BF(cur, 0);
        DO_MFMA();
        VMCNT0;
        BAR; MEMFENCE;
        LOAD_AF(cur, 1);
        LOAD_BF(cur, 1);
        DO_MFMA();
    }

    const int bb_ = mBase >> 11;
#pragma unroll
    for (int m8 = 0; m8 < 8; ++m8) {
        const int row = mBase + wm * 128 + m8 * 16 + g * 4;
        const int s0 = (mBase & 2047) + wm * 128 + m8 * 16 + g * 4;
#pragma unroll
        for (int n3 = 0; n3 < 3; ++n3) {
            const int col = nBase + wn * 48 + n3 * 16 + c15;
            if (col < 2048) {
#pragma unroll
                for (int r = 0; r < 4; ++r)
                    C[(size_t)(row + r) * N + col] = f32_to_bf16_rne(acc[m8][n3][r]);
            } else {
                const int vcol = col - 2048;
                const int hh = vcol >> 6, dd = vcol & 63;
                ushort4 vv;
                vv.x = f32_to_bf16_rne(acc[m8][n3][0]);
                vv.y = f32_to_bf16_rne(acc[m8][n3][1]);
                vv.z = f32_to_bf16_rne(acc[m8][n3][2]);
                vv.w = f32_to_bf16_rne(acc[m8][n3][3]);
                *reinterpret_cast<ushort4*>(
                    &Vt[(((size_t)(bb_ * 16 + hh) * 64 + dd) << 11) + s0]) = vv;
            }
        }
    }
#undef LOAD_AF
#undef LOAD_BF
#undef DO_MFMA
}

// ---------------- 64x128 4-wave counted-vmcnt NT GEMM (f32 + bias out) ----------------
__global__ __launch_bounds__(256, 3) void gemm_out(
    const ushort* __restrict__ A, const ushort* __restrict__ B,
    float* __restrict__ C, const float* __restrict__ bias, int M, int N, int K) {
    __shared__ ushort smem[24576];   // 48 KB

    const int t = threadIdx.x;
    const int l = t & 63, w = t >> 6;      // 4 waves
    const int wm = w >> 1, wn = w & 1;     // 2 x 2
    const int c15 = l & 15, g = l >> 4;
    const int bid = blockIdx.x;            // 512 blocks
    const int swz = (bid & 7) * 64 + (bid >> 3);
    const int mBase = (swz >> 3) * 64, nBase = (swz & 7) * 128;
    const int NT = K >> 6;

    int rA_, k8A_;
    {
        const int L = w * 1024 + l * 16;
        const int rp = L >> 7;
        const int gl = ((L >> 4) & 7) ^ (rp & 7);
        rA_ = rp * 2 + (gl >> 2);
        k8A_ = (gl & 3) * 8;
    }
    int rB_[2], k8B_[2];
#pragma unroll
    for (int j = 0; j < 2; ++j) {
        const int L = (w * 2 + j) * 1024 + l * 16;
        const int rp = L >> 7;
        const int gl = ((L >> 4) & 7) ^ (rp & 7);
        rB_[j] = rp * 2 + (gl >> 2);
        k8B_[j] = (gl & 3) * 8;
    }

    int aOff[2], bOff[4];
#pragma unroll
    for (int m2 = 0; m2 < 2; ++m2) {
        const int R = wm * 32 + m2 * 16 + c15;
        const int rp = R >> 1;
        aOff[m2] = rp * 64 + ((((R & 1) << 2) | g) ^ (rp & 7)) * 8;
    }
#pragma unroll
    for (int n4 = 0; n4 < 4; ++n4) {
        const int R = wn * 64 + n4 * 16 + c15;
        const int rp = R >> 1;
        bOff[n4] = rp * 64 + ((((R & 1) << 2) | g) ^ (rp & 7)) * 8;
    }

    f32x4 acc[2][4] = {};
    bf16x8 aF[2], bF0[2], bF1[2];

    auto stage = [&](int dbuf, int kh, int kt) {
        const ushort* sa = A + (size_t)(mBase + rA_) * K + kt * 64 + kh * 32 + k8A_;
        __builtin_amdgcn_global_load_lds(
            (const __attribute__((address_space(1))) void*)sa,
            (__attribute__((address_space(3))) void*)
                &smem[dbuf * 12288 + kh * 2048 + w * 512 + l * 8],
            16, 0, 0);
#pragma unroll
        for (int j = 0; j < 2; ++j) {
            const ushort* sb = B + (size_t)(nBase + rB_[j]) * K + kt * 64 + kh * 32 + k8B_[j];
            __builtin_amdgcn_global_load_lds(
                (const __attribute__((address_space(1))) void*)sb,
                (__attribute__((address_space(3))) void*)
                    &smem[dbuf * 12288 + 4096 + kh * 4096 + (w * 2 + j) * 512 + l * 8],
                16, 0, 0);
        }
    };

#define LOAD_AF2(CUR, KS)                                                       \
    {                                                                           \
        const int ab = (CUR) * 12288 + (KS) * 2048;                             \
        _Pragma("unroll") for (int m2 = 0; m2 < 2; ++m2)                        \
            aF[m2] = *reinterpret_cast<const bf16x8*>(&smem[ab + aOff[m2]]);    \
    }
#define LOAD_BF2(DST, CUR, KS, NH)                                              \
    {                                                                           \
        const int bb = (CUR) * 12288 + 4096 + (KS) * 4096;                      \
        _Pragma("unroll") for (int n = 0; n < 2; ++n)                           \
            DST[n] = *reinterpret_cast<const bf16x8*>(&smem[bb + bOff[(NH) * 2 + n]]); \
    }
#define DO_MFMA2(NH, BF)                                                        \
    __builtin_amdgcn_s_setprio(1);                                              \
    _Pragma("unroll") for (int m2 = 0; m2 < 2; ++m2) {                          \
        _Pragma("unroll") for (int n = 0; n < 2; ++n)                           \
            acc[m2][(NH) * 2 + n] = __builtin_amdgcn_mfma_f32_16x16x32_bf16(    \
                aF[m2], BF[n], acc[m2][(NH) * 2 + n], 0, 0, 0);                 \
    }                                                                           \
    __builtin_amdgcn_s_setprio(0);

    stage(0, 0, 0);
    stage(0, 1, 0);

    for (int kt = 0; kt < NT - 1; ++kt) {
        const int cur = kt & 1, nxt = cur ^ 1;
        VMCNT3;
        BAR; MEMFENCE;
        LOAD_AF2(cur, 0);
        LOAD_BF2(bF0, cur, 0, 0);
        stage(nxt, 0, kt + 1);
        DO_MFMA2(0, bF0);
        LOAD_BF2(bF1, cur, 0, 1);
        DO_MFMA2(1, bF1);
        VMCNT3;
        BAR; MEMFENCE;
        LOAD_AF2(cur, 1);
        LOAD_BF2(bF0, cur, 1, 0);
        stage(nxt, 1, kt + 1);
        DO_MFMA2(0, bF0);
        LOAD_BF2(bF1, cur, 1, 1);
        DO_MFMA2(1, bF1);
    }

    {
        const int cur = (NT - 1) & 1;
        VMCNT3;
        BAR; MEMFENCE;
        LOAD_AF2(cur, 0);
        LOAD_BF2(bF0, cur, 0, 0);
        DO_MFMA2(0, bF0);
        LOAD_BF2(bF1, cur, 0, 1);
        DO_MFMA2(1, bF1);
        VMCNT0;
        BAR; MEMFENCE;
        LOAD_AF2(cur, 1);
        LOAD_BF2(bF0, cur, 1, 0);
        DO_MFMA2(0, bF0);
        LOAD_BF2(bF1, cur, 1, 1);
        DO_MFMA2(1, bF1);
    }

#pragma unroll
    for (int m2 = 0; m2 < 2; ++m2) {
#pragma unroll
        for (int n4 = 0; n4 < 4; ++n4) {
            const int col = nBase + wn * 64 + n4 * 16 + c15;
#pragma unroll
            for (int r = 0; r < 4; ++r) {
                const int row = mBase + wm * 32 + m2 * 16 + g * 4 + r;
                C[(size_t)row * N + col] = acc[m2][n4][r] + bias[col];
            }
        }
    }
#undef LOAD_AF2
#undef LOAD_BF2
#undef DO_MFMA2
}

// ---------------- banded MFMA attention, block-shared K/V LDS staging ----------------
#define PADW 104
__global__ __launch_bounds__(256, 2) void attn_fused(
    const ushort* __restrict__ qkv, const ushort* __restrict__ Vt,
    ushort* __restrict__ attn_out) {
    __shared__ ushort K_lds[192 * 64];        // 24 KB
    __shared__ ushort V_lds[64 * 192];        // 24 KB
    __shared__ ushort P_lds[4][32 * PADW];    // 26.6 KB

    const int t = threadIdx.x;
    const int lane = t & 63;
    const int wib  = t >> 6;
    const int bid = blockIdx.x;               // 512 blocks, %8==0 -> bijective
    const int swz = (bid & 7) * 64 + (bid >> 3);
    const int qc = swz & 15;
    const int h  = (swz >> 4) & 15;
    const int b  = swz >> 8;
    const int Qs = qc * 128;
    const int qs = Qs + wib * 32;
    const int kstart = qs - 32;
    const int c15 = lane & 15, g = lane >> 4;
    const int qb = qs >> 5;
    const bool edge = (qb == 0) || (qb == 63);

    // Q fragments first (independent of LDS; overlaps staging latency)
    const ushort* Qbase = qkv + (size_t)(b * 2048 + qs) * 3072 + h * 64;
    bf16x8 qf[2][2];
#pragma unroll
    for (int qt = 0; qt < 2; ++qt)
#pragma unroll
        for (int dc = 0; dc < 2; ++dc)
            qf[qt][dc] = *reinterpret_cast<const bf16x8*>(
                Qbase + (size_t)(qt * 16 + c15) * 3072 + dc * 32 + g * 8);

    const ushort* Kglob = qkv + (size_t)b * 2048 * 3072 + 1024 + h * 64;
#pragma unroll
    for (int c = 0; c < 6; ++c) {
        const int G = c * 256 + t;
        const int row = G >> 3, gp = G & 7;
        const int col16 = gp ^ (row & 7);
        int s = Qs - 32 + row;
        s = min(max(s, 0), 2047);
        __builtin_amdgcn_global_load_lds(
            (const __attribute__((address_space(1))) void*)(Kglob + (size_t)s * 3072 + col16 * 8),
            (__attribute__((address_space(3))) void*)&K_lds[G * 8], 16, 0, 0);
    }
    const ushort* Vglob = Vt + ((size_t)(b * 16 + h) * 64) * 2048;
#pragma unroll
    for (int c = 0; c < 6; ++c) {
        const int L = c * 256 + t;
        const int row = L / 24, gp = L % 24;
        const int lg = gp ^ (row & 7);
        int s = Qs - 32 + lg * 8;
        s = min(max(s, 0), 2040);
        __builtin_amdgcn_global_load_lds(
            (const __attribute__((address_space(1))) void*)(Vglob + (size_t)row * 2048 + s),
            (__attribute__((address_space(3))) void*)&V_lds[L * 8], 16, 0, 0);
    }
    __syncthreads();

    f32x4 accS[6][2] = {};
#pragma unroll
    for (int kt = 0; kt < 6; ++kt) {
        const int krl = wib * 32 + kt * 16 + c15;
#pragma unroll
        for (int dc = 0; dc < 2; ++dc) {
            bf16x8 kf = *reinterpret_cast<const bf16x8*>(
                &K_lds[krl * 64 + ((((dc << 2) | g)) ^ (krl & 7)) * 8]);
#pragma unroll
            for (int qt = 0; qt < 2; ++qt)
                accS[kt][qt] = __builtin_amdgcn_mfma_f32_16x16x32_bf16(
                    kf, qf[qt][dc], accS[kt][qt], 0, 0, 0);
        }
    }

    float mx[2] = {-1e30f, -1e30f};
    if (edge) {
#pragma unroll
        for (int kt = 0; kt < 6; ++kt)
#pragma unroll
            for (int qt = 0; qt < 2; ++qt)
#pragma unroll
                for (int r = 0; r < 4; ++r) {
                    const int vk = kt * 16 + g * 4 + r;
                    const int qi = qt * 16 + c15;
                    const int ki = kstart + vk;
                    const int s_row = qs + qi;
                    float val = -1e30f;
                    if (vk >= qi && vk <= qi + 63 && ki >= 0 && ki <= 2047) {
                        float bias = 0.f;
                        if (ki == 0 && s_row <= 32)
                            bias = __logf((float)(33 - s_row));
                        if (ki == 2047 && s_row >= 2016)
                            bias = __logf((float)(s_row - 2015));
                        val = accS[kt][qt][r] * 0.125f + bias;
                    }
                    accS[kt][qt][r] = val;
                    mx[qt] = fmaxf(mx[qt], val);
                }
    } else {
#pragma unroll
        for (int kt = 0; kt < 6; ++kt)
#pragma unroll
            for (int qt = 0; qt < 2; ++qt)
#pragma unroll
                for (int r = 0; r < 4; ++r) {
                    const int vk = kt * 16 + g * 4 + r;
                    const int qi = qt * 16 + c15;
                    float val = -1e30f;
                    if (vk >= qi && vk <= qi + 63)
                        val = accS[kt][qt][r] * 0.125f;
                    accS[kt][qt][r] = val;
                    mx[qt] = fmaxf(mx[qt], val);
                }
    }
#pragma unroll
    for (int qt = 0; qt < 2; ++qt) {
        mx[qt] = fmaxf(mx[qt], __shfl_xor(mx[qt], 16));
        mx[qt] = fmaxf(mx[qt], __shfl_xor(mx[qt], 32));
    }

    float sum[2] = {0.f, 0.f};
#pragma unroll
    for (int kt = 0; kt < 6; ++kt)
#pragma unroll
        for (int qt = 0; qt < 2; ++qt)
#pragma unroll
            for (int r = 0; r < 4; ++r) {
                float p = __expf(accS[kt][qt][r] - mx[qt]);
                accS[kt][qt][r] = p;
                sum[qt] += p;
            }
#pragma unroll
    for (int qt = 0; qt < 2; ++qt) {
        sum[qt] += __shfl_xor(sum[qt], 16);
        sum[qt] += __shfl_xor(sum[qt], 32);
        sum[qt] = 1.f / sum[qt];
    }

#pragma unroll
    for (int kt = 0; kt < 6; ++kt)
#pragma unroll
        for (int qt = 0; qt < 2; ++qt)
#pragma unroll
            for (int r = 0; r < 4; ++r) {
                const int vk = kt * 16 + g * 4 + r;
                const int qi = qt * 16 + c15;
                P_lds[wib][qi * PADW + vk] = f32_to_bf16_rne(accS[kt][qt][r] * sum[qt]);
            }

    f32x4 accO[2][4] = {};
#pragma unroll
    for (int u = 0; u < 3; ++u) {
        bf16x8 pf[2];
#pragma unroll
        for (int qt = 0; qt < 2; ++qt)
            pf[qt] = *reinterpret_cast<const bf16x8*>(
                &P_lds[wib][(qt * 16 + c15) * PADW + u * 32 + g * 8]);
        const int j = 4 * (wib + u) + g;
#pragma unroll
        for (int dt = 0; dt < 4; ++dt) {
            const int vrow = dt * 16 + c15;
            bf16x8 vf = *reinterpret_cast<const bf16x8*>(
                &V_lds[vrow * 192 + ((j ^ (vrow & 7)) * 8)]);
#pragma unroll
            for (int qt = 0; qt < 2; ++qt)
                accO[qt][dt] = __builtin_amdgcn_mfma_f32_16x16x32_bf16(
                    pf[qt], vf, accO[qt][dt], 0, 0, 0);
        }
    }

#pragma unroll
    for (int qt = 0; qt < 2; ++qt)
#pragma unroll
        for (int dt = 0; dt < 4; ++dt)
#pragma unroll
            for (int r = 0; r < 4; ++r) {
                const int row = b * 2048 + qs + qt * 16 + g * 4 + r;
                const int col = h * 64 + dt * 16 + c15;
                attn_out[(size_t)row * 1024 + col] = f32_to_bf16_rne(accO[qt][dt][r]);
            }
}

// ---------------- launch ----------------
extern "C" void kernel_launch(void* const* d_in, const int* in_sizes, int n_in,
                              void* d_out, int out_size, void* d_ws, size_t ws_size,
                              hipStream_t stream) {
    const float* x  = (const float*)d_in[0];
    const float* Wq = (const float*)d_in[2];
    const float* Wk = (const float*)d_in[3];
    const float* Wv = (const float*)d_in[4];
    const float* Wo = (const float*)d_in[5];
    const float* bo = (const float*)d_in[6];

    const int M = 4096;
    const int DIM = 1024;

    ushort* xb   = (ushort*)d_ws;                 // 4096*1024
    ushort* Wqkv = xb + (size_t)M * DIM;          // 3072*1024
    ushort* Wob  = Wqkv + (size_t)3072 * 1024;    // 1024*1024
    ushort* qkv  = Wob + (size_t)1024 * 1024;     // 4096*3072 (V-range unused)
    ushort* attn = qkv + (size_t)M * 3072;        // 4096*1024
    ushort* Vt   = attn + (size_t)M * DIM;        // 2*16*64*2048

    cvt_all<<<8192, 256, 0, stream>>>(
        (const float4*)x, (const float4*)Wq, (const float4*)Wk,
        (const float4*)Wv, (const float4*)Wo,
        (ushort4*)xb, (ushort4*)Wqkv, (ushort4*)Wob);

    gemm256<<<256, 512, 0, stream>>>(xb, Wqkv, qkv, Vt, M, 3072, DIM);

    attn_fused<<<512, 256, 0, stream>>>(qkv, Vt, attn);

    gemm_out<<<512, 256, 0, stream>>>(attn, Wob, (float*)d_out, bo, M, DIM, DIM);
}

// Round 18
// 68.124 us; speedup vs baseline: 1.1719x; 1.0014x over previous
//
#include <hip/hip_runtime.h>
#include <hip/hip_bf16.h>

// CantorMultiheadFusion: x -> QKV proj -> sliding-window(K=64, clipped) MHA -> out proj (+bias)
// B=2 S=2048 DIM=1024 H=16 D=64 K=64
//
// Pipeline (4 launches):
//  1) cvt_all: f32->bf16 for x, [Wq;Wk;Wv], Wo
//  2) gemm256: qkv bf16 = x @ Wqkv^T (128x192 tile, 4 waves (1x4), BK=64, counted-vmcnt
//     2-phase, granule-XOR swizzle, XCD-swizzled; 80KB LDS -> 2 blocks/CU so the two
//     resident blocks cross-cover each other's vmcnt+barrier stalls. Per-wave structure
//     identical to the proven R13 kernel.) V-range columns -> transposed store into Vt.
//  3) attn_fused: 4 waves x 32 q-rows, block-shared K/V LDS staging, Q-hoist (R13 proven)
//  4) gemm_out: out f32 = attn @ Wo^T + bo (64x128 tile, vmcnt(3), grid 512 = 2/CU)

typedef __attribute__((ext_vector_type(8))) short bf16x8;
typedef __attribute__((ext_vector_type(4))) float f32x4;

__device__ __forceinline__ unsigned short f32_to_bf16_rne(float f) {
    unsigned u = __float_as_uint(f);
    u += 0x7FFFu + ((u >> 16) & 1u);
    return (unsigned short)(u >> 16);
}
__device__ __forceinline__ float bf16_to_f32(unsigned short s) {
    return __uint_as_float(((unsigned)s) << 16);
}

#define VMCNT6 asm volatile("s_waitcnt vmcnt(6)" ::: "memory")
#define VMCNT3 asm volatile("s_waitcnt vmcnt(3)" ::: "memory")
#define VMCNT2 asm volatile("s_waitcnt vmcnt(2)" ::: "memory")
#define VMCNT0 asm volatile("s_waitcnt vmcnt(0)" ::: "memory")
#define MEMFENCE asm volatile("" ::: "memory")
#define BAR __builtin_amdgcn_s_barrier()

// ---------------- merged conversion kernel ----------------
__global__ __launch_bounds__(256) void cvt_all(
    const float4* __restrict__ x,
    const float4* __restrict__ Wq, const float4* __restrict__ Wk,
    const float4* __restrict__ Wv, const float4* __restrict__ Wo,
    ushort4* __restrict__ xb, ushort4* __restrict__ wqkv,
    ushort4* __restrict__ wob) {
    const int XN = (4096 * 1024) / 4;
    const int WN = (1024 * 1024) / 4;
    int i = blockIdx.x * 256 + threadIdx.x;
    float4 v;
    ushort4* dst;
    if (i < XN) {
        v = x[i];
        dst = xb + i;
    } else {
        int j = i - XN;
        int w = j >> 18;
        int k = j & (WN - 1);
        const float4* s = (w == 0) ? Wq : (w == 1) ? Wk : (w == 2) ? Wv : Wo;
        v = s[k];
        dst = (w < 3) ? (wqkv + (size_t)w * WN + k) : (wob + k);
    }
    ushort4 o;
    o.x = f32_to_bf16_rne(v.x);
    o.y = f32_to_bf16_rne(v.y);
    o.z = f32_to_bf16_rne(v.z);
    o.w = f32_to_bf16_rne(v.w);
    *dst = o;
}

// ---------------- 128x192 4-wave counted-vmcnt NT GEMM (2 blocks/CU) ----------------
// Per-wave structure identical to R13 (wave tile 128x48, acc[8][3], 48 MFMA/tile).
// LDS per dbuf (40KB): A-k0[8KB] | A-k1[8KB] | B full-K [24KB, [192][64] rows].
// Per-wave per-tile stage issue order [B(6) @ph0, Ak0(2)+Ak1(2) @ph1]:
//   ph0 vmcnt(2): B_t+Ak0_t landed, Ak1_t flies; ph1 vmcnt(6): Ak1_t landed, B_next flies.
__global__ __launch_bounds__(256, 2) void gemm256(
    const ushort* __restrict__ A, const ushort* __restrict__ B,
    ushort* __restrict__ C, ushort* __restrict__ Vt, int M, int N, int K) {
    __shared__ ushort smem[40960];   // 80 KB

    const int t = threadIdx.x;
    const int l = t & 63, w = t >> 6;      // 4 waves, 1 x 4
    const int wn = w & 3;
    const int c15 = l & 15, g = l >> 4;
    const int bid = blockIdx.x;            // 512 blocks (32m x 16n), %8==0 -> bijective
    const int swz = (bid & 7) * 64 + (bid >> 3);
    const int mBase = (swz >> 4) * 128, nBase = (swz & 15) * 192;
    const int NT = K >> 6;

    // A staging geometry (2 chunks/thread per k-half; [128 rows][32 k], row-pair swizzle)
    int rrA[2], k8A[2];
#pragma unroll
    for (int j = 0; j < 2; ++j) {
        const int L = (w * 2 + j) * 1024 + l * 16;   // 0..8191 within 8KB region
        const int rp = L >> 7;
        const int gl = ((L >> 4) & 7) ^ (rp & 7);
        rrA[j] = rp * 2 + (gl >> 2);
        k8A[j] = (gl & 3) * 8;
    }
    // B staging geometry (6 chunks/thread; [192 rows][64 k], row swizzle)
    int rrB[6], k8B[6];
#pragma unroll
    for (int c = 0; c < 6; ++c) {
        const int G = c * 256 + t;                   // 0..1535
        const int row = G >> 3;
        rrB[c] = row;
        k8B[c] = ((G & 7) ^ (row & 7)) * 8;
    }

    int aOff[8], bOff0[3], bOff1[3];
#pragma unroll
    for (int m8 = 0; m8 < 8; ++m8) {
        const int R = m8 * 16 + c15;                 // 0..127
        const int rp = R >> 1;
        aOff[m8] = rp * 64 + ((((R & 1) << 2) | g) ^ (rp & 7)) * 8;
    }
#pragma unroll
    for (int n3 = 0; n3 < 3; ++n3) {
        const int R = wn * 48 + n3 * 16 + c15;       // 0..191
        bOff0[n3] = R * 64 + ((g) ^ (R & 7)) * 8;
        bOff1[n3] = R * 64 + ((4 | g) ^ (R & 7)) * 8;
    }

    f32x4 acc[8][3] = {};
    bf16x8 aF[8], bF[3];

    auto stageA = [&](int dbuf, int kh, int kt) {
#pragma unroll
        for (int j = 0; j < 2; ++j) {
            const ushort* src = A + (size_t)(mBase + rrA[j]) * K + kt * 64 + kh * 32 + k8A[j];
            __builtin_amdgcn_global_load_lds(
                (const __attribute__((address_space(1))) void*)src,
                (__attribute__((address_space(3))) void*)
                    &smem[dbuf * 20480 + kh * 4096 + (w * 2 + j) * 512 + l * 8],
                16, 0, 0);
        }
    };
    auto stageB = [&](int dbuf, int kt) {
#pragma unroll
        for (int c = 0; c < 6; ++c) {
            const ushort* src = B + (size_t)(nBase + rrB[c]) * K + kt * 64 + k8B[c];
            __builtin_amdgcn_global_load_lds(
                (const __attribute__((address_space(1))) void*)src,
                (__attribute__((address_space(3))) void*)
                    &smem[dbuf * 20480 + 8192 + (c * 256 + t) * 8],
                16, 0, 0);
        }
    };

#define LOAD_AF(CUR, KH)                                                        \
    {                                                                           \
        const int ab = (CUR) * 20480 + (KH) * 4096;                             \
        _Pragma("unroll") for (int m8 = 0; m8 < 8; ++m8)                        \
            aF[m8] = *reinterpret_cast<const bf16x8*>(&smem[ab + aOff[m8]]);    \
    }
#define LOAD_BF(CUR, KH)                                                        \
    {                                                                           \
        const int bb = (CUR) * 20480 + 8192;                                    \
        _Pragma("unroll") for (int n = 0; n < 3; ++n)                           \
            bF[n] = *reinterpret_cast<const bf16x8*>(                           \
                &smem[bb + ((KH) ? bOff1[n] : bOff0[n])]);                      \
    }
#define DO_MFMA()                                                               \
    __builtin_amdgcn_s_setprio(1);                                              \
    _Pragma("unroll") for (int m8 = 0; m8 < 8; ++m8) {                          \
        _Pragma("unroll") for (int n = 0; n < 3; ++n)                           \
            acc[m8][n] = __builtin_amdgcn_mfma_f32_16x16x32_bf16(               \
                aF[m8], bF[n], acc[m8][n], 0, 0, 0);                            \
    }                                                                           \
    __builtin_amdgcn_s_setprio(0);

    // prologue: per-wave issue order [B(6), Ak0(2), Ak1(2)] = 10 outstanding
    stageB(0, 0);
    stageA(0, 0, 0);
    stageA(0, 1, 0);

    for (int kt = 0; kt < NT - 1; ++kt) {
        const int cur = kt & 1, nxt = cur ^ 1;
        // ph0: need B_t(6)+Ak0_t(2) -> leave Ak1_t(2) flying
        VMCNT2;
        BAR; MEMFENCE;
        LOAD_AF(cur, 0);
        LOAD_BF(cur, 0);
        stageB(nxt, kt + 1);          // outstanding: Ak1_t(2)+B_next(6)=8
        DO_MFMA();
        // ph1: need Ak1_t -> leave B_next(6) flying
        VMCNT6;
        BAR; MEMFENCE;
        LOAD_AF(cur, 1);
        LOAD_BF(cur, 1);
        stageA(nxt, 0, kt + 1);
        stageA(nxt, 1, kt + 1);       // outstanding: B_next(6)+A_next(4)=10
        DO_MFMA();
    }

    // tail tile (no staging)
    {
        const int cur = (NT - 1) & 1;
        VMCNT2;
        BAR; MEMFENCE;
        LOAD_AF(cur, 0);
        LOAD_BF(cur, 0);
        DO_MFMA();
        VMCNT0;
        BAR; MEMFENCE;
        LOAD_AF(cur, 1);
        LOAD_BF(cur, 1);
        DO_MFMA();
    }

    // epilogue: per-fragment qkv vs Vt routing (2048 boundary is 16-aligned)
    const int bb_ = mBase >> 11;
#pragma unroll
    for (int m8 = 0; m8 < 8; ++m8) {
        const int row = mBase + m8 * 16 + g * 4;
        const int s0 = (mBase & 2047) + m8 * 16 + g * 4;
#pragma unroll
        for (int n3 = 0; n3 < 3; ++n3) {
            const int col = nBase + wn * 48 + n3 * 16 + c15;
            if (col < 2048) {
#pragma unroll
                for (int r = 0; r < 4; ++r)
                    C[(size_t)(row + r) * N + col] = f32_to_bf16_rne(acc[m8][n3][r]);
            } else {
                const int vcol = col - 2048;
                const int hh = vcol >> 6, dd = vcol & 63;
                ushort4 vv;
                vv.x = f32_to_bf16_rne(acc[m8][n3][0]);
                vv.y = f32_to_bf16_rne(acc[m8][n3][1]);
                vv.z = f32_to_bf16_rne(acc[m8][n3][2]);
                vv.w = f32_to_bf16_rne(acc[m8][n3][3]);
                *reinterpret_cast<ushort4*>(
                    &Vt[(((size_t)(bb_ * 16 + hh) * 64 + dd) << 11) + s0]) = vv;
            }
        }
    }
#undef LOAD_AF
#undef LOAD_BF
#undef DO_MFMA
}

// ---------------- 64x128 4-wave counted-vmcnt NT GEMM (f32 + bias out) ----------------
__global__ __launch_bounds__(256, 3) void gemm_out(
    const ushort* __restrict__ A, const ushort* __restrict__ B,
    float* __restrict__ C, const float* __restrict__ bias, int M, int N, int K) {
    __shared__ ushort smem[24576];   // 48 KB

    const int t = threadIdx.x;
    const int l = t & 63, w = t >> 6;      // 4 waves
    const int wm = w >> 1, wn = w & 1;     // 2 x 2
    const int c15 = l & 15, g = l >> 4;
    const int bid = blockIdx.x;            // 512 blocks
    const int swz = (bid & 7) * 64 + (bid >> 3);
    const int mBase = (swz >> 3) * 64, nBase = (swz & 7) * 128;
    const int NT = K >> 6;

    int rA_, k8A_;
    {
        const int L = w * 1024 + l * 16;
        const int rp = L >> 7;
        const int gl = ((L >> 4) & 7) ^ (rp & 7);
        rA_ = rp * 2 + (gl >> 2);
        k8A_ = (gl & 3) * 8;
    }
    int rB_[2], k8B_[2];
#pragma unroll
    for (int j = 0; j < 2; ++j) {
        const int L = (w * 2 + j) * 1024 + l * 16;
        const int rp = L >> 7;
        const int gl = ((L >> 4) & 7) ^ (rp & 7);
        rB_[j] = rp * 2 + (gl >> 2);
        k8B_[j] = (gl & 3) * 8;
    }

    int aOff[2], bOff[4];
#pragma unroll
    for (int m2 = 0; m2 < 2; ++m2) {
        const int R = wm * 32 + m2 * 16 + c15;
        const int rp = R >> 1;
        aOff[m2] = rp * 64 + ((((R & 1) << 2) | g) ^ (rp & 7)) * 8;
    }
#pragma unroll
    for (int n4 = 0; n4 < 4; ++n4) {
        const int R = wn * 64 + n4 * 16 + c15;
        const int rp = R >> 1;
        bOff[n4] = rp * 64 + ((((R & 1) << 2) | g) ^ (rp & 7)) * 8;
    }

    f32x4 acc[2][4] = {};
    bf16x8 aF[2], bF0[2], bF1[2];

    auto stage = [&](int dbuf, int kh, int kt) {
        const ushort* sa = A + (size_t)(mBase + rA_) * K + kt * 64 + kh * 32 + k8A_;
        __builtin_amdgcn_global_load_lds(
            (const __attribute__((address_space(1))) void*)sa,
            (__attribute__((address_space(3))) void*)
                &smem[dbuf * 12288 + kh * 2048 + w * 512 + l * 8],
            16, 0, 0);
#pragma unroll
        for (int j = 0; j < 2; ++j) {
            const ushort* sb = B + (size_t)(nBase + rB_[j]) * K + kt * 64 + kh * 32 + k8B_[j];
            __builtin_amdgcn_global_load_lds(
                (const __attribute__((address_space(1))) void*)sb,
                (__attribute__((address_space(3))) void*)
                    &smem[dbuf * 12288 + 4096 + kh * 4096 + (w * 2 + j) * 512 + l * 8],
                16, 0, 0);
        }
    };

#define LOAD_AF2(CUR, KS)                                                       \
    {                                                                           \
        const int ab = (CUR) * 12288 + (KS) * 2048;                             \
        _Pragma("unroll") for (int m2 = 0; m2 < 2; ++m2)                        \
            aF[m2] = *reinterpret_cast<const bf16x8*>(&smem[ab + aOff[m2]]);    \
    }
#define LOAD_BF2(DST, CUR, KS, NH)                                              \
    {                                                                           \
        const int bb = (CUR) * 12288 + 4096 + (KS) * 4096;                      \
        _Pragma("unroll") for (int n = 0; n < 2; ++n)                           \
            DST[n] = *reinterpret_cast<const bf16x8*>(&smem[bb + bOff[(NH) * 2 + n]]); \
    }
#define DO_MFMA2(NH, BF)                                                        \
    __builtin_amdgcn_s_setprio(1);                                              \
    _Pragma("unroll") for (int m2 = 0; m2 < 2; ++m2) {                          \
        _Pragma("unroll") for (int n = 0; n < 2; ++n)                           \
            acc[m2][(NH) * 2 + n] = __builtin_amdgcn_mfma_f32_16x16x32_bf16(    \
                aF[m2], BF[n], acc[m2][(NH) * 2 + n], 0, 0, 0);                 \
    }                                                                           \
    __builtin_amdgcn_s_setprio(0);

    stage(0, 0, 0);
    stage(0, 1, 0);

    for (int kt = 0; kt < NT - 1; ++kt) {
        const int cur = kt & 1, nxt = cur ^ 1;
        VMCNT3;
        BAR; MEMFENCE;
        LOAD_AF2(cur, 0);
        LOAD_BF2(bF0, cur, 0, 0);
        stage(nxt, 0, kt + 1);
        DO_MFMA2(0, bF0);
        LOAD_BF2(bF1, cur, 0, 1);
        DO_MFMA2(1, bF1);
        VMCNT3;
        BAR; MEMFENCE;
        LOAD_AF2(cur, 1);
        LOAD_BF2(bF0, cur, 1, 0);
        stage(nxt, 1, kt + 1);
        DO_MFMA2(0, bF0);
        LOAD_BF2(bF1, cur, 1, 1);
        DO_MFMA2(1, bF1);
    }

    {
        const int cur = (NT - 1) & 1;
        VMCNT3;
        BAR; MEMFENCE;
        LOAD_AF2(cur, 0);
        LOAD_BF2(bF0, cur, 0, 0);
        DO_MFMA2(0, bF0);
        LOAD_BF2(bF1, cur, 0, 1);
        DO_MFMA2(1, bF1);
        VMCNT0;
        BAR; MEMFENCE;
        LOAD_AF2(cur, 1);
        LOAD_BF2(bF0, cur, 1, 0);
        DO_MFMA2(0, bF0);
        LOAD_BF2(bF1, cur, 1, 1);
        DO_MFMA2(1, bF1);
    }

#pragma unroll
    for (int m2 = 0; m2 < 2; ++m2) {
#pragma unroll
        for (int n4 = 0; n4 < 4; ++n4) {
            const int col = nBase + wn * 64 + n4 * 16 + c15;
#pragma unroll
            for (int r = 0; r < 4; ++r) {
                const int row = mBase + wm * 32 + m2 * 16 + g * 4 + r;
                C[(size_t)row * N + col] = acc[m2][n4][r] + bias[col];
            }
        }
    }
#undef LOAD_AF2
#undef LOAD_BF2
#undef DO_MFMA2
}

// ---------------- banded MFMA attention, block-shared K/V LDS staging ----------------
#define PADW 104
__global__ __launch_bounds__(256, 2) void attn_fused(
    const ushort* __restrict__ qkv, const ushort* __restrict__ Vt,
    ushort* __restrict__ attn_out) {
    __shared__ ushort K_lds[192 * 64];        // 24 KB
    __shared__ ushort V_lds[64 * 192];        // 24 KB
    __shared__ ushort P_lds[4][32 * PADW];    // 26.6 KB

    const int t = threadIdx.x;
    const int lane = t & 63;
    const int wib  = t >> 6;
    const int bid = blockIdx.x;               // 512 blocks, %8==0 -> bijective
    const int swz = (bid & 7) * 64 + (bid >> 3);
    const int qc = swz & 15;
    const int h  = (swz >> 4) & 15;
    const int b  = swz >> 8;
    const int Qs = qc * 128;
    const int qs = Qs + wib * 32;
    const int kstart = qs - 32;
    const int c15 = lane & 15, g = lane >> 4;
    const int qb = qs >> 5;
    const bool edge = (qb == 0) || (qb == 63);

    // Q fragments first (independent of LDS; overlaps staging latency)
    const ushort* Qbase = qkv + (size_t)(b * 2048 + qs) * 3072 + h * 64;
    bf16x8 qf[2][2];
#pragma unroll
    for (int qt = 0; qt < 2; ++qt)
#pragma unroll
        for (int dc = 0; dc < 2; ++dc)
            qf[qt][dc] = *reinterpret_cast<const bf16x8*>(
                Qbase + (size_t)(qt * 16 + c15) * 3072 + dc * 32 + g * 8);

    const ushort* Kglob = qkv + (size_t)b * 2048 * 3072 + 1024 + h * 64;
#pragma unroll
    for (int c = 0; c < 6; ++c) {
        const int G = c * 256 + t;
        const int row = G >> 3, gp = G & 7;
        const int col16 = gp ^ (row & 7);
        int s = Qs - 32 + row;
        s = min(max(s, 0), 2047);
        __builtin_amdgcn_global_load_lds(
            (const __attribute__((address_space(1))) void*)(Kglob + (size_t)s * 3072 + col16 * 8),
            (__attribute__((address_space(3))) void*)&K_lds[G * 8], 16, 0, 0);
    }
    const ushort* Vglob = Vt + ((size_t)(b * 16 + h) * 64) * 2048;
#pragma unroll
    for (int c = 0; c < 6; ++c) {
        const int L = c * 256 + t;
        const int row = L / 24, gp = L % 24;
        const int lg = gp ^ (row & 7);
        int s = Qs - 32 + lg * 8;
        s = min(max(s, 0), 2040);
        __builtin_amdgcn_global_load_lds(
            (const __attribute__((address_space(1))) void*)(Vglob + (size_t)row * 2048 + s),
            (__attribute__((address_space(3))) void*)&V_lds[L * 8], 16, 0, 0);
    }
    __syncthreads();

    f32x4 accS[6][2] = {};
#pragma unroll
    for (int kt = 0; kt < 6; ++kt) {
        const int krl = wib * 32 + kt * 16 + c15;
#pragma unroll
        for (int dc = 0; dc < 2; ++dc) {
            bf16x8 kf = *reinterpret_cast<const bf16x8*>(
                &K_lds[krl * 64 + ((((dc << 2) | g)) ^ (krl & 7)) * 8]);
#pragma unroll
            for (int qt = 0; qt < 2; ++qt)
                accS[kt][qt] = __builtin_amdgcn_mfma_f32_16x16x32_bf16(
                    kf, qf[qt][dc], accS[kt][qt], 0, 0, 0);
        }
    }

    float mx[2] = {-1e30f, -1e30f};
    if (edge) {
#pragma unroll
        for (int kt = 0; kt < 6; ++kt)
#pragma unroll
            for (int qt = 0; qt < 2; ++qt)
#pragma unroll
                for (int r = 0; r < 4; ++r) {
                    const int vk = kt * 16 + g * 4 + r;
                    const int qi = qt * 16 + c15;
                    const int ki = kstart + vk;
                    const int s_row = qs + qi;
                    float val = -1e30f;
                    if (vk >= qi && vk <= qi + 63 && ki >= 0 && ki <= 2047) {
                        float bias = 0.f;
                        if (ki == 0 && s_row <= 32)
                            bias = __logf((float)(33 - s_row));
                        if (ki == 2047 && s_row >= 2016)
                            bias = __logf((float)(s_row - 2015));
                        val = accS[kt][qt][r] * 0.125f + bias;
                    }
                    accS[kt][qt][r] = val;
                    mx[qt] = fmaxf(mx[qt], val);
                }
    } else {
#pragma unroll
        for (int kt = 0; kt < 6; ++kt)
#pragma unroll
            for (int qt = 0; qt < 2; ++qt)
#pragma unroll
                for (int r = 0; r < 4; ++r) {
                    const int vk = kt * 16 + g * 4 + r;
                    const int qi = qt * 16 + c15;
                    float val = -1e30f;
                    if (vk >= qi && vk <= qi + 63)
                        val = accS[kt][qt][r] * 0.125f;
                    accS[kt][qt][r] = val;
                    mx[qt] = fmaxf(mx[qt], val);
                }
    }
#pragma unroll
    for (int qt = 0; qt < 2; ++qt) {
        mx[qt] = fmaxf(mx[qt], __shfl_xor(mx[qt], 16));
        mx[qt] = fmaxf(mx[qt], __shfl_xor(mx[qt], 32));
    }

    float sum[2] = {0.f, 0.f};
#pragma unroll
    for (int kt = 0; kt < 6; ++kt)
#pragma unroll
        for (int qt = 0; qt < 2; ++qt)
#pragma unroll
            for (int r = 0; r < 4; ++r) {
                float p = __expf(accS[kt][qt][r] - mx[qt]);
                accS[kt][qt][r] = p;
                sum[qt] += p;
            }
#pragma unroll
    for (int qt = 0; qt < 2; ++qt) {
        sum[qt] += __shfl_xor(sum[qt], 16);
        sum[qt] += __shfl_xor(sum[qt], 32);
        sum[qt] = 1.f / sum[qt];
    }

#pragma unroll
    for (int kt = 0; kt < 6; ++kt)
#pragma unroll
        for (int qt = 0; qt < 2; ++qt)
#pragma unroll
            for (int r = 0; r < 4; ++r) {
                const int vk = kt * 16 + g * 4 + r;
                const int qi = qt * 16 + c15;
                P_lds[wib][qi * PADW + vk] = f32_to_bf16_rne(accS[kt][qt][r] * sum[qt]);
            }

    f32x4 accO[2][4] = {};
#pragma unroll
    for (int u = 0; u < 3; ++u) {
        bf16x8 pf[2];
#pragma unroll
        for (int qt = 0; qt < 2; ++qt)
            pf[qt] = *reinterpret_cast<const bf16x8*>(
                &P_lds[wib][(qt * 16 + c15) * PADW + u * 32 + g * 8]);
        const int j = 4 * (wib + u) + g;
#pragma unroll
        for (int dt = 0; dt < 4; ++dt) {
            const int vrow = dt * 16 + c15;
            bf16x8 vf = *reinterpret_cast<const bf16x8*>(
                &V_lds[vrow * 192 + ((j ^ (vrow & 7)) * 8)]);
#pragma unroll
            for (int qt = 0; qt < 2; ++qt)
                accO[qt][dt] = __builtin_amdgcn_mfma_f32_16x16x32_bf16(
                    pf[qt], vf, accO[qt][dt], 0, 0, 0);
        }
    }

#pragma unroll
    for (int qt = 0; qt < 2; ++qt)
#pragma unroll
        for (int dt = 0; dt < 4; ++dt)
#pragma unroll
            for (int r = 0; r < 4; ++r) {
                const int row = b * 2048 + qs + qt * 16 + g * 4 + r;
                const int col = h * 64 + dt * 16 + c15;
                attn_out[(size_t)row * 1024 + col] = f32_to_bf16_rne(accO[qt][dt][r]);
            }
}

// ---------------- launch ----------------
extern "C" void kernel_launch(void* const* d_in, const int* in_sizes, int n_in,
                              void* d_out, int out_size, void* d_ws, size_t ws_size,
                              hipStream_t stream) {
    const float* x  = (const float*)d_in[0];
    const float* Wq = (const float*)d_in[2];
    const float* Wk = (const float*)d_in[3];
    const float* Wv = (const float*)d_in[4];
    const float* Wo = (const float*)d_in[5];
    const float* bo = (const float*)d_in[6];

    const int M = 4096;
    const int DIM = 1024;

    ushort* xb   = (ushort*)d_ws;                 // 4096*1024
    ushort* Wqkv = xb + (size_t)M * DIM;          // 3072*1024
    ushort* Wob  = Wqkv + (size_t)3072 * 1024;    // 1024*1024
    ushort* qkv  = Wob + (size_t)1024 * 1024;     // 4096*3072 (V-range unused)
    ushort* attn = qkv + (size_t)M * 3072;        // 4096*1024
    ushort* Vt   = attn + (size_t)M * DIM;        // 2*16*64*2048

    cvt_all<<<8192, 256, 0, stream>>>(
        (const float4*)x, (const float4*)Wq, (const float4*)Wk,
        (const float4*)Wv, (const float4*)Wo,
        (ushort4*)xb, (ushort4*)Wqkv, (ushort4*)Wob);

    gemm256<<<512, 256, 0, stream>>>(xb, Wqkv, qkv, Vt, M, 3072, DIM);

    attn_fused<<<512, 256, 0, stream>>>(qkv, Vt, attn);

    gemm_out<<<512, 256, 0, stream>>>(attn, Wob, (float*)d_out, bo, M, DIM, DIM);
}